// Round 2
// baseline (642.327 us; speedup 1.0000x reference)
//
#include <hip/hip_runtime.h>
#include <math.h>

// Problem geometry (fixed by reference)
#define N_ROWS 32768          // 32 * 32 * 32 (B*H*W)
#define K_CODES 1024
#define C_DIM 256
#define HW 1024               // H*W = 32*32

// d_out layout (float elements), tuple concatenated flat in return order:
// distances [N,K] | indices [N] (as float) | encodings [N,K] | perplexity [1]
#define OFF_DIST 0
#define OFF_IDX  (N_ROWS * K_CODES)
#define OFF_ENC  (OFF_IDX + N_ROWS)
#define OFF_PERP (OFF_ENC + N_ROWS * K_CODES)

// ---------------- z row norms: zsq[n] = sum_c z_e[b][c][hw]^2 ----------------
// n = b*1024 + hw; addr = b*C*HW + c*HW + hw. For fixed c, consecutive n are
// consecutive in memory -> coalesced across the wave.
__global__ __launch_bounds__(256) void zsq_kernel(const float* __restrict__ z,
                                                  float* __restrict__ zsq) {
    int n = blockIdx.x * 256 + threadIdx.x;
    int b = n >> 10;
    int hw = n & 1023;
    const float* p = z + (size_t)b * (C_DIM * HW) + hw;
    float s = 0.f;
#pragma unroll 8
    for (int c = 0; c < C_DIM; ++c) {
        float v = p[(size_t)c * HW];
        s = fmaf(v, v, s);
    }
    zsq[n] = s;
}

// ---------------- codebook norms: esq[k] = sum_c codebook[k][c]^2 ------------
__global__ __launch_bounds__(256) void esq_kernel(const float* __restrict__ cb,
                                                  float* __restrict__ esq) {
    int k = blockIdx.x * 256 + threadIdx.x;
    const float4* p = reinterpret_cast<const float4*>(cb + (size_t)k * C_DIM);
    float s = 0.f;
#pragma unroll 4
    for (int c4 = 0; c4 < C_DIM / 4; ++c4) {
        float4 v = p[c4];
        s = fmaf(v.x, v.x, s);
        s = fmaf(v.y, v.y, s);
        s = fmaf(v.z, v.z, s);
        s = fmaf(v.w, v.w, s);
    }
    esq[k] = s;
}

// ---------------- distances GEMM: dist[n][k] = zsq[n]+esq[k]-2*z.e -----------
// 64x64 output tile per 256-thread block, 4x4 micro-tile per thread,
// C staged in CK=16-wide chunks through LDS.
#define BT 64
#define CK 16

__global__ __launch_bounds__(256) void dist_kernel(const float* __restrict__ z,
                                                   const float* __restrict__ cb,
                                                   const float* __restrict__ zsq,
                                                   const float* __restrict__ esq,
                                                   float* __restrict__ dist) {
    __shared__ float zt[CK][BT + 1];   // [c][n]  (+1 pad: conflict-free)
    __shared__ float ct[CK][BT + 1];   // [c][k]

    const int ktile = blockIdx.x;          // 16 tiles of K
    const int ntile = blockIdx.y;          // 512 tiles of N
    const int n0 = ntile * BT;
    const int k0 = ktile * BT;
    const int b = n0 >> 10;                // 64 | 1024 -> tile within one batch b
    const int hw0 = n0 & 1023;

    const int t  = threadIdx.x;
    const int tx = t & 15;                 // 16 k-groups
    const int ty = t >> 4;                 // 16 n-groups

    const float* zbase = z + (size_t)b * (C_DIM * HW) + hw0;

    float acc[4][4] = {};

    for (int c0 = 0; c0 < C_DIM; c0 += CK) {
        // z tile: 16 c x 64 n. Lane-consecutive n -> coalesced 256B segments.
        {
            int cl = t >> 6;               // 0..3
            int nl = t & 63;
#pragma unroll
            for (int r = 0; r < 4; ++r) {
                int cc = cl + r * 4;
                zt[cc][nl] = zbase[(size_t)(c0 + cc) * HW + nl];
            }
        }
        // codebook tile: 64 k x 16 c, float4 along c, stored transposed.
        {
            int kl = t >> 2;               // 0..63
            int c4 = (t & 3) * 4;
            float4 v = *reinterpret_cast<const float4*>(
                cb + (size_t)(k0 + kl) * C_DIM + c0 + c4);
            ct[c4 + 0][kl] = v.x;
            ct[c4 + 1][kl] = v.y;
            ct[c4 + 2][kl] = v.z;
            ct[c4 + 3][kl] = v.w;
        }
        __syncthreads();

#pragma unroll
        for (int cl = 0; cl < CK; ++cl) {
            float av[4], bv[4];
#pragma unroll
            for (int i = 0; i < 4; ++i) av[i] = zt[cl][ty * 4 + i];
#pragma unroll
            for (int j = 0; j < 4; ++j) bv[j] = ct[cl][tx * 4 + j];
#pragma unroll
            for (int i = 0; i < 4; ++i)
#pragma unroll
                for (int j = 0; j < 4; ++j)
                    acc[i][j] = fmaf(av[i], bv[j], acc[i][j]);
        }
        __syncthreads();
    }

    // epilogue: dist = zsq + esq - 2*dot, float4 stores
    float es[4];
#pragma unroll
    for (int j = 0; j < 4; ++j) es[j] = esq[k0 + tx * 4 + j];
#pragma unroll
    for (int i = 0; i < 4; ++i) {
        int n = n0 + ty * 4 + i;
        float zs = zsq[n];
        float4 o;
        o.x = zs + es[0] - 2.f * acc[i][0];
        o.y = zs + es[1] - 2.f * acc[i][1];
        o.z = zs + es[2] - 2.f * acc[i][2];
        o.w = zs + es[3] - 2.f * acc[i][3];
        *reinterpret_cast<float4*>(dist + (size_t)n * K_CODES + k0 + tx * 4) = o;
    }
}

// ---------------- argmin + one-hot encodings + histogram ---------------------
// One block per row. Tie-break: smallest k (jnp.argmin first-occurrence).
__global__ __launch_bounds__(256) void argmin_kernel(const float* __restrict__ dist,
                                                     float* __restrict__ idx_out,
                                                     float* __restrict__ enc,
                                                     int* __restrict__ counts) {
    const int n = blockIdx.x;
    const int t = threadIdx.x;
    const float* row = dist + (size_t)n * K_CODES;

    float best = INFINITY;
    int bi = K_CODES;
#pragma unroll
    for (int r = 0; r < 4; ++r) {
        int k = t + r * 256;               // ascending k per thread
        float d = row[k];
        if (d < best) { best = d; bi = k; }
    }
    // wave (64-lane) reduce
#pragma unroll
    for (int off = 32; off > 0; off >>= 1) {
        float ob = __shfl_down(best, off);
        int   oi = __shfl_down(bi, off);
        if (ob < best || (ob == best && oi < bi)) { best = ob; bi = oi; }
    }
    __shared__ float sb[4];
    __shared__ int   si[4];
    __shared__ int   bestIdx;
    int wid = t >> 6;
    if ((t & 63) == 0) { sb[wid] = best; si[wid] = bi; }
    __syncthreads();
    if (t == 0) {
#pragma unroll
        for (int w = 1; w < 4; ++w) {
            if (sb[w] < sb[0] || (sb[w] == sb[0] && si[w] < si[0])) {
                sb[0] = sb[w]; si[0] = si[w];
            }
        }
        bestIdx = si[0];
        idx_out[n] = (float)si[0];
        atomicAdd(&counts[si[0]], 1);
    }
    __syncthreads();
    const int bidx = bestIdx;
    float* erow = enc + (size_t)n * K_CODES;
#pragma unroll
    for (int r = 0; r < 4; ++r) {
        int k = t + r * 256;
        erow[k] = (k == bidx) ? 1.0f : 0.0f;
    }
}

// ---------------- perplexity -------------------------------------------------
__global__ __launch_bounds__(256) void perp_kernel(const int* __restrict__ counts,
                                                   float* __restrict__ out) {
    const int t = threadIdx.x;
    double s = 0.0;
#pragma unroll
    for (int r = 0; r < 4; ++r) {
        int k = t + r * 256;
        double p = (double)counts[k] / (double)N_ROWS;
        s += p * log(p + 1e-10);
    }
#pragma unroll
    for (int off = 32; off > 0; off >>= 1) s += __shfl_down(s, off);
    __shared__ double wsum[4];
    int wid = t >> 6;
    if ((t & 63) == 0) wsum[wid] = s;
    __syncthreads();
    if (t == 0) {
        double tot = wsum[0] + wsum[1] + wsum[2] + wsum[3];
        out[0] = (float)exp(-tot);
    }
}

extern "C" void kernel_launch(void* const* d_in, const int* in_sizes, int n_in,
                              void* d_out, int out_size, void* d_ws, size_t ws_size,
                              hipStream_t stream) {
    const float* z  = (const float*)d_in[0];   // [32,256,32,32]
    const float* cb = (const float*)d_in[1];   // [1024,256]
    float* out  = (float*)d_out;
    float* dist = out + OFF_DIST;
    float* idxo = out + OFF_IDX;
    float* enc  = out + OFF_ENC;
    float* perp = out + OFF_PERP;

    float* zsq    = (float*)d_ws;              // 32768 floats
    float* esq    = zsq + N_ROWS;              // 1024 floats
    int*   counts = (int*)(esq + K_CODES);     // 1024 ints

    hipMemsetAsync(counts, 0, K_CODES * sizeof(int), stream);
    zsq_kernel<<<N_ROWS / 256, 256, 0, stream>>>(z, zsq);
    esq_kernel<<<K_CODES / 256, 256, 0, stream>>>(cb, esq);
    dim3 grid(K_CODES / BT, N_ROWS / BT);
    dist_kernel<<<grid, 256, 0, stream>>>(z, cb, zsq, esq, dist);
    argmin_kernel<<<N_ROWS, 256, 0, stream>>>(dist, idxo, enc, counts);
    perp_kernel<<<1, 256, 0, stream>>>(counts, perp);
}

// Round 3
// 574.956 us; speedup vs baseline: 1.1172x; 1.1172x over previous
//
#include <hip/hip_runtime.h>
#include <math.h>

// Problem geometry (fixed by reference)
#define N_ROWS 32768          // 32 * 32 * 32 (B*H*W)
#define K_CODES 1024
#define C_DIM 256
#define HW 1024               // H*W = 32*32

// d_out layout (float elements), tuple concatenated flat in return order:
// distances [N,K] | indices [N] (as float) | encodings [N,K] | perplexity [1]
#define OFF_DIST 0
#define OFF_IDX  (N_ROWS * K_CODES)
#define OFF_ENC  (OFF_IDX + N_ROWS)
#define OFF_PERP (OFF_ENC + N_ROWS * K_CODES)

typedef __attribute__((ext_vector_type(8))) short short8;   // 8 bf16 (4 VGPR)
typedef __attribute__((ext_vector_type(4))) float f32x4;    // MFMA acc

// ---- bf16 split helpers (bit-level, round-to-nearest-even) ------------------
__device__ inline unsigned short bf16_rn(float x) {
    unsigned int u = __float_as_uint(x);
    unsigned int r = u + 0x7FFFu + ((u >> 16) & 1u);
    return (unsigned short)(r >> 16);
}
__device__ inline float bf16_to_f(unsigned short h) {
    return __uint_as_float(((unsigned int)h) << 16);
}

// ---------------- z row norms: zsq[n] = sum_c z_e[b][c][hw]^2 ----------------
__global__ __launch_bounds__(256) void zsq_kernel(const float* __restrict__ z,
                                                  float* __restrict__ zsq) {
    int n = blockIdx.x * 256 + threadIdx.x;
    int b = n >> 10;
    int hw = n & 1023;
    const float* p = z + (size_t)b * (C_DIM * HW) + hw;
    float s = 0.f;
#pragma unroll 8
    for (int c = 0; c < C_DIM; ++c) {
        float v = p[(size_t)c * HW];
        s = fmaf(v, v, s);
    }
    zsq[n] = s;
}

// ------- codebook: esq[k] = ||e_k||^2, plus fp32 -> bf16 hi/lo split ---------
__global__ __launch_bounds__(256) void prep_cb(const float* __restrict__ cb,
                                               float* __restrict__ esq,
                                               unsigned short* __restrict__ cb_hi,
                                               unsigned short* __restrict__ cb_lo) {
    int k = blockIdx.x * 256 + threadIdx.x;   // grid 4 -> k in [0,1024)
    const float4* p = reinterpret_cast<const float4*>(cb + (size_t)k * C_DIM);
    float s = 0.f;
#pragma unroll 4
    for (int c4 = 0; c4 < C_DIM / 4; ++c4) {
        float4 v = p[c4];
        s = fmaf(v.x, v.x, s);
        s = fmaf(v.y, v.y, s);
        s = fmaf(v.z, v.z, s);
        s = fmaf(v.w, v.w, s);
        ushort4 h, l;
        h.x = bf16_rn(v.x); l.x = bf16_rn(v.x - bf16_to_f(h.x));
        h.y = bf16_rn(v.y); l.y = bf16_rn(v.y - bf16_to_f(h.y));
        h.z = bf16_rn(v.z); l.z = bf16_rn(v.z - bf16_to_f(h.z));
        h.w = bf16_rn(v.w); l.w = bf16_rn(v.w - bf16_to_f(h.w));
        *reinterpret_cast<ushort4*>(cb_hi + (size_t)k * C_DIM + c4 * 4) = h;
        *reinterpret_cast<ushort4*>(cb_lo + (size_t)k * C_DIM + c4 * 4) = l;
    }
    esq[k] = s;
}

// -------- distances via bf16x4-split MFMA + fused partial argmin -------------
// Block: 256 thr (4 waves, 2x2 wave grid). Tile: BM=64 rows x BN=256 codes.
// Wave tile 32x128: mi in {0,1} (16-row frags), ci in 0..7 (16-col frags).
// Grid: (K/BN=4, N/BM=512). Partial argmin per (row, kb-tile) -> ws.
#define BM 64
#define BN 256
#define BK 32

__global__ __launch_bounds__(256) void dist_mfma_kernel(
        const float* __restrict__ z,
        const unsigned short* __restrict__ cb_hi,
        const unsigned short* __restrict__ cb_lo,
        const float* __restrict__ zsq, const float* __restrict__ esq,
        float* __restrict__ dist, float2* __restrict__ partial) {
    __shared__ float st[BK][BM + 1];      // staged fp32 z tile [c][n], 2-way max
    __shared__ float2 pb[BM][2];          // per-row candidates from wx=0/1

    const int t = threadIdx.x;
    const int lane = t & 63, wid = t >> 6;
    const int wy = wid >> 1, wx = wid & 1;
    const int l15 = lane & 15, l4 = lane >> 4;

    const int nb = blockIdx.y * BM;       // global row base
    const int kb = blockIdx.x * BN;       // global col base
    const int b = nb >> 10, hw0 = nb & 1023;
    const float* zbase = z + (size_t)b * (C_DIM * HW) + hw0;

    // staging role: thread t loads c = t>>3, n-octet = (t&7)*8
    const int sc = t >> 3;
    const int sn = (t & 7) * 8;

    f32x4 acc[2][8] = {};                 // zero-initialized

    for (int c0 = 0; c0 < C_DIM; c0 += BK) {
        // ---- stage z fp32 [32 c][64 n], coalesced along n ----
        const float* gp = zbase + (size_t)(c0 + sc) * HW + sn;
        float4 v0 = *reinterpret_cast<const float4*>(gp);
        float4 v1 = *reinterpret_cast<const float4*>(gp + 4);
        st[sc][sn + 0] = v0.x; st[sc][sn + 1] = v0.y;
        st[sc][sn + 2] = v0.z; st[sc][sn + 3] = v0.w;
        st[sc][sn + 4] = v1.x; st[sc][sn + 5] = v1.y;
        st[sc][sn + 6] = v1.z; st[sc][sn + 7] = v1.w;
        __syncthreads();

        // ---- B fragments straight from global (L2-hot bf16 codebook) ----
        // B[k=c][col=code] = cb[code][c]; lane: col = l15, k-octet = l4*8+i
        short8 bh[8], bl[8];
        const int ccol = c0 + l4 * 8;
#pragma unroll
        for (int ci = 0; ci < 8; ++ci) {
            int code = kb + wx * 128 + ci * 16 + l15;
            bh[ci] = *reinterpret_cast<const short8*>(cb_hi + (size_t)code * C_DIM + ccol);
            bl[ci] = *reinterpret_cast<const short8*>(cb_lo + (size_t)code * C_DIM + ccol);
        }

        // ---- A fragments from LDS + hi/lo split ----
        // lane: row = l15 (+mi*16 + wy*32), k-octet = l4*8+i
        short8 ah[2], al[2];
#pragma unroll
        for (int mi = 0; mi < 2; ++mi) {
            int rl = wy * 32 + mi * 16 + l15;
#pragma unroll
            for (int i = 0; i < 8; ++i) {
                float x = st[l4 * 8 + i][rl];
                unsigned short h = bf16_rn(x);
                float lo = x - bf16_to_f(h);
                ah[mi][i] = (short)h;
                al[mi][i] = (short)bf16_rn(lo);
            }
        }

        // ---- MFMA: (ah+al)(bh+bl), all 4 products into same fp32 acc ----
#pragma unroll
        for (int mi = 0; mi < 2; ++mi)
#pragma unroll
            for (int ci = 0; ci < 8; ++ci) {
                acc[mi][ci] = __builtin_amdgcn_mfma_f32_16x16x32_bf16(ah[mi], bh[ci], acc[mi][ci], 0, 0, 0);
                acc[mi][ci] = __builtin_amdgcn_mfma_f32_16x16x32_bf16(ah[mi], bl[ci], acc[mi][ci], 0, 0, 0);
                acc[mi][ci] = __builtin_amdgcn_mfma_f32_16x16x32_bf16(al[mi], bh[ci], acc[mi][ci], 0, 0, 0);
                acc[mi][ci] = __builtin_amdgcn_mfma_f32_16x16x32_bf16(al[mi], bl[ci], acc[mi][ci], 0, 0, 0);
            }
        __syncthreads();
    }

    // ---- epilogue: dist = zsq + esq - 2*dot; write + per-row partial argmin
    float zs[2][4];
#pragma unroll
    for (int mi = 0; mi < 2; ++mi)
#pragma unroll
        for (int r = 0; r < 4; ++r)
            zs[mi][r] = zsq[nb + wy * 32 + mi * 16 + l4 * 4 + r];
    float es[8];
#pragma unroll
    for (int ci = 0; ci < 8; ++ci)
        es[ci] = esq[kb + wx * 128 + ci * 16 + l15];

    float best[2][4];
    int bidx[2][4];
#pragma unroll
    for (int mi = 0; mi < 2; ++mi)
#pragma unroll
        for (int r = 0; r < 4; ++r) { best[mi][r] = 1e30f; bidx[mi][r] = K_CODES; }

#pragma unroll
    for (int mi = 0; mi < 2; ++mi) {
#pragma unroll
        for (int r = 0; r < 4; ++r) {
            int row = nb + wy * 32 + mi * 16 + l4 * 4 + r;
            float* drow = dist + (size_t)row * K_CODES;
#pragma unroll
            for (int ci = 0; ci < 8; ++ci) {     // ci ascending = k ascending
                int col = kb + wx * 128 + ci * 16 + l15;
                float d = zs[mi][r] + es[ci] - 2.f * acc[mi][ci][r];
                drow[col] = d;
                if (d < best[mi][r]) { best[mi][r] = d; bidx[mi][r] = col; }
            }
        }
    }

    // reduce across the 16-lane column group (xor masks 1,2,4,8 stay in-group)
#pragma unroll
    for (int m = 1; m < 16; m <<= 1) {
#pragma unroll
        for (int mi = 0; mi < 2; ++mi)
#pragma unroll
            for (int r = 0; r < 4; ++r) {
                float ob = __shfl_xor(best[mi][r], m);
                int   oi = __shfl_xor(bidx[mi][r], m);
                if (ob < best[mi][r] || (ob == best[mi][r] && oi < bidx[mi][r])) {
                    best[mi][r] = ob; bidx[mi][r] = oi;
                }
            }
    }

    if (l15 == 0) {
#pragma unroll
        for (int mi = 0; mi < 2; ++mi)
#pragma unroll
            for (int r = 0; r < 4; ++r) {
                int rl = wy * 32 + mi * 16 + l4 * 4 + r;
                pb[rl][wx] = make_float2(best[mi][r], (float)bidx[mi][r]);
            }
    }
    __syncthreads();
    if (t < BM) {
        float2 a = pb[t][0], c = pb[t][1];
        float2 rr = (c.x < a.x) ? c : a;      // tie -> wx=0 (smaller k)
        partial[(size_t)blockIdx.x * N_ROWS + nb + t] = rr;
    }
}

// -------- combine 4 kb-partials -> final index + histogram -------------------
__global__ __launch_bounds__(256) void combine_kernel(const float2* __restrict__ partial,
                                                      float* __restrict__ idx_out,
                                                      int* __restrict__ idx_int,
                                                      int* __restrict__ counts) {
    int n = blockIdx.x * 256 + threadIdx.x;
    float2 bv = partial[n];
#pragma unroll
    for (int kb = 1; kb < 4; ++kb) {          // ascending kb = ascending k
        float2 c = partial[(size_t)kb * N_ROWS + n];
        if (c.x < bv.x) bv = c;
    }
    int k = (int)bv.y;
    idx_out[n] = bv.y;
    idx_int[n] = k;
    atomicAdd(&counts[k], 1);
}

// -------- one-hot encodings (coalesced float4 stream) ------------------------
__global__ __launch_bounds__(256) void enc_kernel(const int* __restrict__ idx_int,
                                                  float* __restrict__ enc) {
    const int t = threadIdx.x;
    const int r0 = blockIdx.x * 16;
    const int k0 = t * 4;
#pragma unroll 4
    for (int r = 0; r < 16; ++r) {
        int n = r0 + r;
        int bi = idx_int[n];
        float4 v;
        v.x = (k0 + 0 == bi) ? 1.0f : 0.0f;
        v.y = (k0 + 1 == bi) ? 1.0f : 0.0f;
        v.z = (k0 + 2 == bi) ? 1.0f : 0.0f;
        v.w = (k0 + 3 == bi) ? 1.0f : 0.0f;
        *reinterpret_cast<float4*>(enc + (size_t)n * K_CODES + k0) = v;
    }
}

// ---------------- perplexity -------------------------------------------------
__global__ __launch_bounds__(256) void perp_kernel(const int* __restrict__ counts,
                                                   float* __restrict__ out) {
    const int t = threadIdx.x;
    double s = 0.0;
#pragma unroll
    for (int r = 0; r < 4; ++r) {
        int k = t + r * 256;
        double p = (double)counts[k] / (double)N_ROWS;
        s += p * log(p + 1e-10);
    }
#pragma unroll
    for (int off = 32; off > 0; off >>= 1) s += __shfl_down(s, off);
    __shared__ double wsum[4];
    int wid = t >> 6;
    if ((t & 63) == 0) wsum[wid] = s;
    __syncthreads();
    if (t == 0) {
        double tot = wsum[0] + wsum[1] + wsum[2] + wsum[3];
        out[0] = (float)exp(-tot);
    }
}

extern "C" void kernel_launch(void* const* d_in, const int* in_sizes, int n_in,
                              void* d_out, int out_size, void* d_ws, size_t ws_size,
                              hipStream_t stream) {
    const float* z  = (const float*)d_in[0];   // [32,256,32,32]
    const float* cb = (const float*)d_in[1];   // [1024,256]
    float* out  = (float*)d_out;
    float* dist = out + OFF_DIST;
    float* idxo = out + OFF_IDX;
    float* enc  = out + OFF_ENC;
    float* perp = out + OFF_PERP;

    // ws layout (bytes, 16B-aligned sections), total ~2.3 MB
    char* wsb = (char*)d_ws;
    float*          zsq    = (float*)(wsb + 0);                    // 131072 B
    float*          esq    = (float*)(wsb + 131072);               //   4096 B
    int*            counts = (int*)(wsb + 135168);                 //   4096 B
    int*            idxi   = (int*)(wsb + 139264);                 // 131072 B
    unsigned short* cb_hi  = (unsigned short*)(wsb + 270336);      // 524288 B
    unsigned short* cb_lo  = (unsigned short*)(wsb + 794624);      // 524288 B
    float2*         part   = (float2*)(wsb + 1318912);             // 1 MB

    hipMemsetAsync(counts, 0, K_CODES * sizeof(int), stream);
    prep_cb<<<K_CODES / 256, 256, 0, stream>>>(cb, esq, cb_hi, cb_lo);
    zsq_kernel<<<N_ROWS / 256, 256, 0, stream>>>(z, zsq);
    dim3 dg(K_CODES / BN, N_ROWS / BM);
    dist_mfma_kernel<<<dg, 256, 0, stream>>>(z, cb_hi, cb_lo, zsq, esq, dist, part);
    combine_kernel<<<N_ROWS / 256, 256, 0, stream>>>(part, idxo, idxi, counts);
    enc_kernel<<<N_ROWS / 16, 256, 0, stream>>>(idxi, enc);
    perp_kernel<<<1, 256, 0, stream>>>(counts, perp);
}

// Round 4
// 505.389 us; speedup vs baseline: 1.2710x; 1.1376x over previous
//
#include <hip/hip_runtime.h>
#include <math.h>

// Problem geometry (fixed by reference)
#define N_ROWS 32768          // 32 * 32 * 32 (B*H*W)
#define K_CODES 1024
#define C_DIM 256
#define HW 1024               // H*W = 32*32

// d_out layout (float elements), tuple concatenated flat in return order:
// distances [N,K] | indices [N] (as float) | encodings [N,K] | perplexity [1]
#define OFF_DIST 0
#define OFF_IDX  (N_ROWS * K_CODES)
#define OFF_ENC  (OFF_IDX + N_ROWS)
#define OFF_PERP (OFF_ENC + N_ROWS * K_CODES)

typedef __attribute__((ext_vector_type(8))) short short8;   // 8 bf16 (4 VGPR)
typedef __attribute__((ext_vector_type(4))) float f32x4;    // MFMA acc

// ---- bf16 split helpers (bit-level, round-to-nearest-even) ------------------
__device__ inline unsigned short bf16_rn(float x) {
    unsigned int u = __float_as_uint(x);
    unsigned int r = u + 0x7FFFu + ((u >> 16) & 1u);
    return (unsigned short)(r >> 16);
}
__device__ inline float bf16_to_f(unsigned short h) {
    return __uint_as_float(((unsigned int)h) << 16);
}

// ------- codebook: esq[k] = ||e_k||^2, fp32 -> bf16 hi/lo split --------------
// One wave per codebook row; lane l owns c = l*4..l*4+3.
__global__ __launch_bounds__(256) void prep_cb(const float* __restrict__ cb,
                                               float* __restrict__ esq,
                                               unsigned short* __restrict__ cb_hi,
                                               unsigned short* __restrict__ cb_lo) {
    const int t = threadIdx.x;
    const int lane = t & 63;
    const int k = blockIdx.x * 4 + (t >> 6);
    float4 v = *reinterpret_cast<const float4*>(cb + (size_t)k * C_DIM + lane * 4);
    float s = v.x * v.x + v.y * v.y + v.z * v.z + v.w * v.w;
    ushort4 h, l;
    h.x = bf16_rn(v.x); l.x = bf16_rn(v.x - bf16_to_f(h.x));
    h.y = bf16_rn(v.y); l.y = bf16_rn(v.y - bf16_to_f(h.y));
    h.z = bf16_rn(v.z); l.z = bf16_rn(v.z - bf16_to_f(h.z));
    h.w = bf16_rn(v.w); l.w = bf16_rn(v.w - bf16_to_f(h.w));
    *reinterpret_cast<ushort4*>(cb_hi + (size_t)k * C_DIM + lane * 4) = h;
    *reinterpret_cast<ushort4*>(cb_lo + (size_t)k * C_DIM + lane * 4) = l;
#pragma unroll
    for (int m = 1; m < 64; m <<= 1) s += __shfl_xor(s, m);
    if (lane == 0) esq[k] = s;
}

// ------- z: NCHW fp32 -> NHWC bf16 hi/lo planes + fused zsq ------------------
// Block: one b, 128 hw. LDS-tiled transpose in 64-c chunks.
__global__ __launch_bounds__(256) void prep_z(const float* __restrict__ z,
                                              unsigned short* __restrict__ z_hi,
                                              unsigned short* __restrict__ z_lo,
                                              float* __restrict__ zsq) {
    __shared__ float st[64][132];          // [c][hw], row = 528 B (16B-aligned)

    const int t = threadIdx.x;
    const int b = blockIdx.y;
    const int hw0 = blockIdx.x * 128;

    const int c_r  = t >> 5;               // 0..7  (read role)
    const int hw_r = (t & 31) * 4;
    const int hw_w = t >> 1;               // 0..127 (write role)
    const int ch   = (t & 1) * 32;
    const int n    = b * HW + hw0 + hw_w;

    float zacc = 0.f;

    for (int c0 = 0; c0 < C_DIM; c0 += 64) {
        // read [64 c][128 hw] coalesced along hw
#pragma unroll
        for (int it = 0; it < 8; ++it) {
            int c_l = it * 8 + c_r;
            float4 v = *reinterpret_cast<const float4*>(
                z + (size_t)b * (C_DIM * HW) + (size_t)(c0 + c_l) * HW + hw0 + hw_r);
            *reinterpret_cast<float4*>(&st[c_l][hw_r]) = v;
        }
        __syncthreads();

        // transpose out: thread owns (hw_w, 32 c's), split hi/lo, accumulate sq
        short8 hv[4], lv[4];
#pragma unroll
        for (int j = 0; j < 32; ++j) {
            float x = st[ch + j][hw_w];
            unsigned short h = bf16_rn(x);
            unsigned short lo = bf16_rn(x - bf16_to_f(h));
            hv[j >> 3][j & 7] = (short)h;
            lv[j >> 3][j & 7] = (short)lo;
            zacc = fmaf(x, x, zacc);
        }
        unsigned short* hp = z_hi + (size_t)n * C_DIM + c0 + ch;
        unsigned short* lp = z_lo + (size_t)n * C_DIM + c0 + ch;
#pragma unroll
        for (int q = 0; q < 4; ++q) {
            *reinterpret_cast<short8*>(hp + q * 8) = hv[q];
            *reinterpret_cast<short8*>(lp + q * 8) = lv[q];
        }
        __syncthreads();
    }
    // pair (t, t^1) covers all 256 c of row n
    float o = __shfl_xor(zacc, 1);
    if ((t & 1) == 0) zsq[n] = zacc + o;
}

// -------- distances via 3-product bf16-split MFMA, no LDS, no K-loop barriers
// Block: 256 thr (4 waves, 2x2). Tile: 64 rows x 256 codes. Grid: 2048 1D.
__global__ __launch_bounds__(256) void dist_mfma_kernel(
        const unsigned short* __restrict__ z_hi,
        const unsigned short* __restrict__ z_lo,
        const unsigned short* __restrict__ cb_hi,
        const unsigned short* __restrict__ cb_lo,
        const float* __restrict__ zsq, const float* __restrict__ esq,
        float* __restrict__ dist, float2* __restrict__ partial) {
    __shared__ float2 pb[64][2];

    const int t = threadIdx.x;
    const int lane = t & 63, wid = t >> 6;
    const int wy = wid >> 1, wx = wid & 1;
    const int l15 = lane & 15, l4 = lane >> 4;

    const int kbi = blockIdx.x >> 9;            // 0..3
    const int kb = kbi * 256;
    const int nb = (blockIdx.x & 511) * 64;

    const int row0 = nb + wy * 32 + l15;        // mi=0 rows
    const unsigned short* a0h = z_hi + (size_t)row0 * C_DIM + l4 * 8;
    const unsigned short* a0l = z_lo + (size_t)row0 * C_DIM + l4 * 8;
    const unsigned short* bbh = cb_hi + (size_t)(kb + wx * 128 + l15) * C_DIM + l4 * 8;
    const unsigned short* bbl = cb_lo + (size_t)(kb + wx * 128 + l15) * C_DIM + l4 * 8;

    f32x4 acc[2][8] = {};

#pragma unroll 2
    for (int c0 = 0; c0 < C_DIM; c0 += 32) {
        short8 ah0 = *reinterpret_cast<const short8*>(a0h + c0);
        short8 al0 = *reinterpret_cast<const short8*>(a0l + c0);
        short8 ah1 = *reinterpret_cast<const short8*>(a0h + 16 * C_DIM + c0);
        short8 al1 = *reinterpret_cast<const short8*>(a0l + 16 * C_DIM + c0);
#pragma unroll
        for (int ci = 0; ci < 8; ++ci) {
            short8 bh = *reinterpret_cast<const short8*>(bbh + (size_t)ci * 16 * C_DIM + c0);
            short8 bl = *reinterpret_cast<const short8*>(bbl + (size_t)ci * 16 * C_DIM + c0);
            acc[0][ci] = __builtin_amdgcn_mfma_f32_16x16x32_bf16(ah0, bh, acc[0][ci], 0, 0, 0);
            acc[0][ci] = __builtin_amdgcn_mfma_f32_16x16x32_bf16(ah0, bl, acc[0][ci], 0, 0, 0);
            acc[0][ci] = __builtin_amdgcn_mfma_f32_16x16x32_bf16(al0, bh, acc[0][ci], 0, 0, 0);
            acc[1][ci] = __builtin_amdgcn_mfma_f32_16x16x32_bf16(ah1, bh, acc[1][ci], 0, 0, 0);
            acc[1][ci] = __builtin_amdgcn_mfma_f32_16x16x32_bf16(ah1, bl, acc[1][ci], 0, 0, 0);
            acc[1][ci] = __builtin_amdgcn_mfma_f32_16x16x32_bf16(al1, bh, acc[1][ci], 0, 0, 0);
        }
    }

    // ---- epilogue: dist = zsq + esq - 2*dot; write + per-row partial argmin
    float zs[2][4];
#pragma unroll
    for (int mi = 0; mi < 2; ++mi)
#pragma unroll
        for (int r = 0; r < 4; ++r)
            zs[mi][r] = zsq[nb + wy * 32 + mi * 16 + l4 * 4 + r];
    float es[8];
#pragma unroll
    for (int ci = 0; ci < 8; ++ci)
        es[ci] = esq[kb + wx * 128 + ci * 16 + l15];

    float best[2][4];
    int bidx[2][4];
#pragma unroll
    for (int mi = 0; mi < 2; ++mi)
#pragma unroll
        for (int r = 0; r < 4; ++r) { best[mi][r] = 1e30f; bidx[mi][r] = K_CODES; }

#pragma unroll
    for (int mi = 0; mi < 2; ++mi) {
#pragma unroll
        for (int r = 0; r < 4; ++r) {
            int row = nb + wy * 32 + mi * 16 + l4 * 4 + r;
            float* drow = dist + (size_t)row * K_CODES;
#pragma unroll
            for (int ci = 0; ci < 8; ++ci) {     // ci ascending = k ascending
                int col = kb + wx * 128 + ci * 16 + l15;
                float d = zs[mi][r] + es[ci] - 2.f * acc[mi][ci][r];
                drow[col] = d;
                if (d < best[mi][r]) { best[mi][r] = d; bidx[mi][r] = col; }
            }
        }
    }

    // reduce across the 16-lane column group (xor masks 1,2,4,8 stay in-group)
#pragma unroll
    for (int m = 1; m < 16; m <<= 1) {
#pragma unroll
        for (int mi = 0; mi < 2; ++mi)
#pragma unroll
            for (int r = 0; r < 4; ++r) {
                float ob = __shfl_xor(best[mi][r], m);
                int   oi = __shfl_xor(bidx[mi][r], m);
                if (ob < best[mi][r] || (ob == best[mi][r] && oi < bidx[mi][r])) {
                    best[mi][r] = ob; bidx[mi][r] = oi;
                }
            }
    }

    if (l15 == 0) {
#pragma unroll
        for (int mi = 0; mi < 2; ++mi)
#pragma unroll
            for (int r = 0; r < 4; ++r) {
                int rl = wy * 32 + mi * 16 + l4 * 4 + r;
                pb[rl][wx] = make_float2(best[mi][r], (float)bidx[mi][r]);
            }
    }
    __syncthreads();
    if (t < 64) {
        float2 a = pb[t][0], c = pb[t][1];
        float2 rr = (c.x < a.x) ? c : a;      // tie -> wx=0 (smaller k)
        partial[(size_t)kbi * N_ROWS + nb + t] = rr;
    }
}

// -------- combine 4 kb-partials -> final index + histogram -------------------
__global__ __launch_bounds__(256) void combine_kernel(const float2* __restrict__ partial,
                                                      float* __restrict__ idx_out,
                                                      int* __restrict__ idx_int,
                                                      int* __restrict__ counts) {
    int n = blockIdx.x * 256 + threadIdx.x;
    float2 bv = partial[n];
#pragma unroll
    for (int kb = 1; kb < 4; ++kb) {          // ascending kb = ascending k
        float2 c = partial[(size_t)kb * N_ROWS + n];
        if (c.x < bv.x) bv = c;
    }
    int k = (int)bv.y;
    idx_out[n] = bv.y;
    idx_int[n] = k;
    atomicAdd(&counts[k], 1);
}

// -------- one-hot encodings (coalesced float4 stream) ------------------------
__global__ __launch_bounds__(256) void enc_kernel(const int* __restrict__ idx_int,
                                                  float* __restrict__ enc) {
    const int t = threadIdx.x;
    const int r0 = blockIdx.x * 16;
    const int k0 = t * 4;
#pragma unroll 4
    for (int r = 0; r < 16; ++r) {
        int n = r0 + r;
        int bi = idx_int[n];
        float4 v;
        v.x = (k0 + 0 == bi) ? 1.0f : 0.0f;
        v.y = (k0 + 1 == bi) ? 1.0f : 0.0f;
        v.z = (k0 + 2 == bi) ? 1.0f : 0.0f;
        v.w = (k0 + 3 == bi) ? 1.0f : 0.0f;
        *reinterpret_cast<float4*>(enc + (size_t)n * K_CODES + k0) = v;
    }
}

// ---------------- perplexity (f32, matches ref dtype) ------------------------
__global__ __launch_bounds__(256) void perp_kernel(const int* __restrict__ counts,
                                                   float* __restrict__ out) {
    const int t = threadIdx.x;
    float s = 0.f;
#pragma unroll
    for (int r = 0; r < 4; ++r) {
        int k = t + r * 256;
        float p = (float)counts[k] * (1.0f / (float)N_ROWS);
        s += p * logf(p + 1e-10f);
    }
#pragma unroll
    for (int off = 32; off > 0; off >>= 1) s += __shfl_down(s, off);
    __shared__ float wsum[4];
    int wid = t >> 6;
    if ((t & 63) == 0) wsum[wid] = s;
    __syncthreads();
    if (t == 0) {
        float tot = wsum[0] + wsum[1] + wsum[2] + wsum[3];
        out[0] = expf(-tot);
    }
}

extern "C" void kernel_launch(void* const* d_in, const int* in_sizes, int n_in,
                              void* d_out, int out_size, void* d_ws, size_t ws_size,
                              hipStream_t stream) {
    const float* z  = (const float*)d_in[0];   // [32,256,32,32]
    const float* cb = (const float*)d_in[1];   // [1024,256]
    float* out  = (float*)d_out;
    float* dist = out + OFF_DIST;
    float* idxo = out + OFF_IDX;
    float* enc  = out + OFF_ENC;
    float* perp = out + OFF_PERP;

    // ws layout (bytes, 16B-aligned sections), total ~2.4 MB (same as r3)
    char* wsb = (char*)d_ws;
    float*          zsq    = (float*)(wsb + 0);                    // 131072 B
    float*          esq    = (float*)(wsb + 131072);               //   4096 B
    int*            counts = (int*)(wsb + 135168);                 //   4096 B
    int*            idxi   = (int*)(wsb + 139264);                 // 131072 B
    unsigned short* cb_hi  = (unsigned short*)(wsb + 270336);      // 524288 B
    unsigned short* cb_lo  = (unsigned short*)(wsb + 794624);      // 524288 B
    float2*         part   = (float2*)(wsb + 1318912);             // 1 MB

    // z_hi/z_lo (32 MB) live in the enc region of d_out: written by prep_z,
    // consumed by dist_mfma, then overwritten by enc_kernel at the end.
    unsigned short* z_hi = (unsigned short*)enc;
    unsigned short* z_lo = z_hi + (size_t)N_ROWS * C_DIM;

    hipMemsetAsync(counts, 0, K_CODES * sizeof(int), stream);
    prep_cb<<<K_CODES / 4, 256, 0, stream>>>(cb, esq, cb_hi, cb_lo);
    dim3 zg(HW / 128, 32);
    prep_z<<<zg, 256, 0, stream>>>(z, z_hi, z_lo, zsq);
    dist_mfma_kernel<<<2048, 256, 0, stream>>>(z_hi, z_lo, cb_hi, cb_lo,
                                               zsq, esq, dist, part);
    combine_kernel<<<N_ROWS / 256, 256, 0, stream>>>(part, idxo, idxi, counts);
    enc_kernel<<<N_ROWS / 16, 256, 0, stream>>>(idxi, enc);
    perp_kernel<<<1, 256, 0, stream>>>(counts, perp);
}

// Round 5
// 442.265 us; speedup vs baseline: 1.4524x; 1.1427x over previous
//
#include <hip/hip_runtime.h>
#include <math.h>

// Problem geometry (fixed by reference)
#define N_ROWS 32768          // 32 * 32 * 32 (B*H*W)
#define K_CODES 1024
#define C_DIM 256
#define HW 1024               // H*W = 32*32

// d_out layout (float elements), tuple concatenated flat in return order:
// distances [N,K] | indices [N] (as float) | encodings [N,K] | perplexity [1]
#define OFF_DIST 0
#define OFF_IDX  (N_ROWS * K_CODES)
#define OFF_ENC  (OFF_IDX + N_ROWS)
#define OFF_PERP (OFF_ENC + N_ROWS * K_CODES)

typedef __attribute__((ext_vector_type(8))) short short8;   // 8 bf16 (4 VGPR)
typedef __attribute__((ext_vector_type(4))) float f32x4;    // MFMA acc

// ---- bf16 split helpers (bit-level, round-to-nearest-even) ------------------
__device__ inline unsigned short bf16_rn(float x) {
    unsigned int u = __float_as_uint(x);
    unsigned int r = u + 0x7FFFu + ((u >> 16) & 1u);
    return (unsigned short)(r >> 16);
}
__device__ inline float bf16_to_f(unsigned short h) {
    return __uint_as_float(((unsigned int)h) << 16);
}

// ---- async global->LDS, 16B per lane (dest = wave-uniform base + lane*16) ---
__device__ __forceinline__ void gl2lds16(const unsigned short* g, char* l) {
    __builtin_amdgcn_global_load_lds(
        (const __attribute__((address_space(1))) unsigned int*)g,
        (__attribute__((address_space(3))) unsigned int*)l, 16, 0, 0);
}

// ------- fused prep: z NCHW->NHWC hi/lo + zsq  |  codebook hi/lo + esq -------
// blocks 0..255: z role (b = bid>>3, hw-tile = bid&7). blocks 256..511: cb.
__global__ __launch_bounds__(256) void prep_kernel(
        const float* __restrict__ z, const float* __restrict__ cb,
        unsigned short* __restrict__ z_hi, unsigned short* __restrict__ z_lo,
        unsigned short* __restrict__ cb_hi, unsigned short* __restrict__ cb_lo,
        float* __restrict__ zsq, float* __restrict__ esq) {
    const int bid = blockIdx.x;
    const int t = threadIdx.x;

    if (bid >= 256) {          // ---- codebook role: wave per row ----
        const int lane = t & 63;
        const int k = (bid - 256) * 4 + (t >> 6);
        float4 v = *reinterpret_cast<const float4*>(cb + (size_t)k * C_DIM + lane * 4);
        float s = v.x * v.x + v.y * v.y + v.z * v.z + v.w * v.w;
        ushort4 h, l;
        h.x = bf16_rn(v.x); l.x = bf16_rn(v.x - bf16_to_f(h.x));
        h.y = bf16_rn(v.y); l.y = bf16_rn(v.y - bf16_to_f(h.y));
        h.z = bf16_rn(v.z); l.z = bf16_rn(v.z - bf16_to_f(h.z));
        h.w = bf16_rn(v.w); l.w = bf16_rn(v.w - bf16_to_f(h.w));
        *reinterpret_cast<ushort4*>(cb_hi + (size_t)k * C_DIM + lane * 4) = h;
        *reinterpret_cast<ushort4*>(cb_lo + (size_t)k * C_DIM + lane * 4) = l;
#pragma unroll
        for (int m = 1; m < 64; m <<= 1) s += __shfl_xor(s, m);
        if (lane == 0) esq[k] = s;
        return;
    }

    // ---- z role: LDS-tiled NCHW -> NHWC transpose + hi/lo split + zsq ----
    __shared__ float st[64][132];          // [c][hw]
    const int b = bid >> 3;
    const int hw0 = (bid & 7) * 128;

    const int c_r  = t >> 5;               // 0..7  (read role)
    const int hw_r = (t & 31) * 4;
    const int hw_w = t >> 1;               // 0..127 (write role)
    const int ch   = (t & 1) * 32;
    const int n    = b * HW + hw0 + hw_w;

    float zacc = 0.f;

    for (int c0 = 0; c0 < C_DIM; c0 += 64) {
#pragma unroll
        for (int it = 0; it < 8; ++it) {
            int c_l = it * 8 + c_r;
            float4 v = *reinterpret_cast<const float4*>(
                z + (size_t)b * (C_DIM * HW) + (size_t)(c0 + c_l) * HW + hw0 + hw_r);
            *reinterpret_cast<float4*>(&st[c_l][hw_r]) = v;
        }
        __syncthreads();

        short8 hv[4], lv[4];
#pragma unroll
        for (int j = 0; j < 32; ++j) {
            float x = st[ch + j][hw_w];
            unsigned short h = bf16_rn(x);
            unsigned short lo = bf16_rn(x - bf16_to_f(h));
            hv[j >> 3][j & 7] = (short)h;
            lv[j >> 3][j & 7] = (short)lo;
            zacc = fmaf(x, x, zacc);
        }
        unsigned short* hp = z_hi + (size_t)n * C_DIM + c0 + ch;
        unsigned short* lp = z_lo + (size_t)n * C_DIM + c0 + ch;
#pragma unroll
        for (int q = 0; q < 4; ++q) {
            *reinterpret_cast<short8*>(hp + q * 8) = hv[q];
            *reinterpret_cast<short8*>(lp + q * 8) = lv[q];
        }
        __syncthreads();
    }
    float o = __shfl_xor(zacc, 1);
    if ((t & 1) == 0) zsq[n] = zacc + o;
}

// -------- distances: m97-structure bf16 GEMM over virtual K=768 --------------
// 128x128 tile, BK=32, 4 waves (2x2, 64x64 each), double-buffered LDS fed by
// global_load_lds(16B), ds_read_b128 fragments, 16 MFMA / wave / K-step.
// Virtual K: steps 0-7 = Ah*Bh, 8-15 = Ah*Bl, 16-23 = Al*Bh (c0 = (s&7)*32).
#define KSTEPS 24

__global__ __launch_bounds__(256) void dist_mfma_kernel(
        const unsigned short* __restrict__ z_hi,
        const unsigned short* __restrict__ z_lo,
        const unsigned short* __restrict__ cb_hi,
        const unsigned short* __restrict__ cb_lo,
        const float* __restrict__ zsq, const float* __restrict__ esq,
        float* __restrict__ dist, float2* __restrict__ partial) {
    __shared__ __align__(16) unsigned short As[2][128 * 32];
    __shared__ __align__(16) unsigned short Bs[2][128 * 32];
    __shared__ float2 pb[128][2];

    const int t = threadIdx.x;
    const int lane = t & 63, wid = t >> 6;
    const int wy = wid >> 1, wx = wid & 1;
    const int l15 = lane & 15, l4 = lane >> 4;

    const int kbi = blockIdx.x & 7;             // 8 column tiles
    const int kb = kbi * 128;
    const int nb = (blockIdx.x >> 3) * 128;     // 256 row tiles

    // staging: 512 chunks of 16B per tile; thread t does chunks t and 256+t.
#define STAGE(buf_, s_) do {                                                   \
        const int sp_ = (s_) >> 3;                                             \
        const int sc0_ = ((s_) & 7) * 32;                                      \
        const unsigned short* Ap_ = (sp_ == 2) ? z_lo : z_hi;                  \
        const unsigned short* Bp_ = (sp_ == 1) ? cb_lo : cb_hi;                \
        _Pragma("unroll")                                                      \
        for (int j_ = 0; j_ < 2; ++j_) {                                       \
            int ch_ = j_ * 256 + t;                                            \
            int row_ = ch_ >> 2, oct_ = ch_ & 3;                               \
            int lb_ = (j_ * 256 + (t & 192)) * 16;                             \
            gl2lds16(Ap_ + (size_t)(nb + row_) * C_DIM + sc0_ + oct_ * 8,      \
                     (char*)(&As[buf_][0]) + lb_);                             \
            gl2lds16(Bp_ + (size_t)(kb + row_) * C_DIM + sc0_ + oct_ * 8,      \
                     (char*)(&Bs[buf_][0]) + lb_);                             \
        }                                                                      \
    } while (0)

    f32x4 acc[4][4] = {};

    STAGE(0, 0);
    __syncthreads();

    for (int s = 0; s < KSTEPS; ++s) {
        const int cur = s & 1;
        if (s < KSTEPS - 1) STAGE(cur ^ 1, s + 1);

        short8 av[4], bv[4];
#pragma unroll
        for (int mi = 0; mi < 4; ++mi)
            av[mi] = *reinterpret_cast<const short8*>(
                &As[cur][(wy * 64 + mi * 16 + l15) * 32 + l4 * 8]);
#pragma unroll
        for (int ci = 0; ci < 4; ++ci)
            bv[ci] = *reinterpret_cast<const short8*>(
                &Bs[cur][(wx * 64 + ci * 16 + l15) * 32 + l4 * 8]);

#pragma unroll
        for (int mi = 0; mi < 4; ++mi)
#pragma unroll
            for (int ci = 0; ci < 4; ++ci)
                acc[mi][ci] = __builtin_amdgcn_mfma_f32_16x16x32_bf16(
                    av[mi], bv[ci], acc[mi][ci], 0, 0, 0);
        __syncthreads();
    }
#undef STAGE

    // ---- epilogue: dist = zsq + esq - 2*dot; write + per-row partial argmin
    float zsv[4][4];
#pragma unroll
    for (int mi = 0; mi < 4; ++mi)
#pragma unroll
        for (int r = 0; r < 4; ++r)
            zsv[mi][r] = zsq[nb + wy * 64 + mi * 16 + l4 * 4 + r];
    float esv[4];
#pragma unroll
    for (int ci = 0; ci < 4; ++ci)
        esv[ci] = esq[kb + wx * 64 + ci * 16 + l15];

    float best[4][4];
    int bidx[4][4];
#pragma unroll
    for (int mi = 0; mi < 4; ++mi)
#pragma unroll
        for (int r = 0; r < 4; ++r) { best[mi][r] = 1e30f; bidx[mi][r] = K_CODES; }

#pragma unroll
    for (int mi = 0; mi < 4; ++mi) {
#pragma unroll
        for (int r = 0; r < 4; ++r) {
            int row = nb + wy * 64 + mi * 16 + l4 * 4 + r;
            float* drow = dist + (size_t)row * K_CODES;
#pragma unroll
            for (int ci = 0; ci < 4; ++ci) {     // ci ascending = k ascending
                int col = kb + wx * 64 + ci * 16 + l15;
                float d = zsv[mi][r] + esv[ci] - 2.f * acc[mi][ci][r];
                drow[col] = d;
                if (d < best[mi][r]) { best[mi][r] = d; bidx[mi][r] = col; }
            }
        }
    }

    // reduce across the 16-lane column group (xor masks 1,2,4,8 vary l15 only)
#pragma unroll
    for (int m = 1; m < 16; m <<= 1) {
#pragma unroll
        for (int mi = 0; mi < 4; ++mi)
#pragma unroll
            for (int r = 0; r < 4; ++r) {
                float ob = __shfl_xor(best[mi][r], m);
                int   oi = __shfl_xor(bidx[mi][r], m);
                if (ob < best[mi][r] || (ob == best[mi][r] && oi < bidx[mi][r])) {
                    best[mi][r] = ob; bidx[mi][r] = oi;
                }
            }
    }

    if (l15 == 0) {
#pragma unroll
        for (int mi = 0; mi < 4; ++mi)
#pragma unroll
            for (int r = 0; r < 4; ++r) {
                int rl = wy * 64 + mi * 16 + l4 * 4 + r;
                pb[rl][wx] = make_float2(best[mi][r], (float)bidx[mi][r]);
            }
    }
    __syncthreads();
    if (t < 128) {
        float2 a = pb[t][0], c = pb[t][1];
        float2 rr = (c.x < a.x) ? c : a;      // tie -> wx=0 (smaller k)
        partial[(size_t)kbi * N_ROWS + nb + t] = rr;
    }
}

// -------- combine 8 kb-partials + one-hot encodings (fused) ------------------
__global__ __launch_bounds__(256) void combenc_kernel(
        const float2* __restrict__ partial, float* __restrict__ idx_out,
        int* __restrict__ idx_int, float* __restrict__ enc) {
    __shared__ int sidx[16];
    const int t = threadIdx.x;
    const int r0 = blockIdx.x * 16;
    if (t < 16) {
        int n = r0 + t;
        float2 bv = partial[n];
#pragma unroll
        for (int kb = 1; kb < 8; ++kb) {      // ascending kb = ascending k
            float2 c = partial[(size_t)kb * N_ROWS + n];
            if (c.x < bv.x) bv = c;
        }
        idx_out[n] = bv.y;
        idx_int[n] = (int)bv.y;
        sidx[t] = (int)bv.y;
    }
    __syncthreads();
    const int k0 = t * 4;
#pragma unroll 4
    for (int r = 0; r < 16; ++r) {
        int bi = sidx[r];
        float4 v;
        v.x = (k0 + 0 == bi) ? 1.0f : 0.0f;
        v.y = (k0 + 1 == bi) ? 1.0f : 0.0f;
        v.z = (k0 + 2 == bi) ? 1.0f : 0.0f;
        v.w = (k0 + 3 == bi) ? 1.0f : 0.0f;
        *reinterpret_cast<float4*>(enc + (size_t)(r0 + r) * K_CODES + k0) = v;
    }
}

// ---------------- perplexity: LDS histogram of idxi + reduce -----------------
__global__ __launch_bounds__(1024) void perp_kernel(const int* __restrict__ idxi,
                                                    float* __restrict__ out) {
    __shared__ int hist[K_CODES];
    __shared__ float wsum[16];
    const int t = threadIdx.x;
    hist[t] = 0;
    __syncthreads();
    for (int n = t; n < N_ROWS; n += 1024)
        atomicAdd(&hist[idxi[n]], 1);
    __syncthreads();
    float p = (float)hist[t] * (1.0f / (float)N_ROWS);
    float s = p * logf(p + 1e-10f);
#pragma unroll
    for (int off = 32; off > 0; off >>= 1) s += __shfl_down(s, off);
    if ((t & 63) == 0) wsum[t >> 6] = s;
    __syncthreads();
    if (t == 0) {
        float tot = 0.f;
#pragma unroll
        for (int w = 0; w < 16; ++w) tot += wsum[w];
        out[0] = expf(-tot);
    }
}

extern "C" void kernel_launch(void* const* d_in, const int* in_sizes, int n_in,
                              void* d_out, int out_size, void* d_ws, size_t ws_size,
                              hipStream_t stream) {
    const float* z  = (const float*)d_in[0];   // [32,256,32,32]
    const float* cb = (const float*)d_in[1];   // [1024,256]
    float* out  = (float*)d_out;
    float* dist = out + OFF_DIST;
    float* idxo = out + OFF_IDX;
    float* enc  = out + OFF_ENC;
    float* perp = out + OFF_PERP;

    // ws layout (bytes), total ~2.26 MB (same footprint class as round 4)
    char* wsb = (char*)d_ws;
    float*  zsq  = (float*)(wsb + 0);          // 131072 B
    float*  esq  = (float*)(wsb + 131072);     //   4096 B
    int*    idxi = (int*)(wsb + 135168);       // 131072 B
    float2* part = (float2*)(wsb + 266240);    // 8*32768*8 = 2097152 B

    // Big staging buffers live in the enc region of d_out (128 MB): written by
    // prep, read by dist, then overwritten by combenc (strict stream order).
    unsigned short* z_hi  = (unsigned short*)enc;
    unsigned short* z_lo  = z_hi + (size_t)N_ROWS * C_DIM;     // +16 MB
    unsigned short* cb_hi = z_lo + (size_t)N_ROWS * C_DIM;     // +32 MB
    unsigned short* cb_lo = cb_hi + (size_t)K_CODES * C_DIM;   // +32.5 MB

    prep_kernel<<<512, 256, 0, stream>>>(z, cb, z_hi, z_lo, cb_hi, cb_lo, zsq, esq);
    dist_mfma_kernel<<<2048, 256, 0, stream>>>(z_hi, z_lo, cb_hi, cb_lo,
                                               zsq, esq, dist, part);
    combenc_kernel<<<N_ROWS / 16, 256, 0, stream>>>(part, idxo, idxi, enc);
    perp_kernel<<<1, 1024, 0, stream>>>(idxi, perp);
}

// Round 6
// 390.078 us; speedup vs baseline: 1.6467x; 1.1338x over previous
//
#include <hip/hip_runtime.h>
#include <math.h>

// Problem geometry (fixed by reference)
#define N_ROWS 32768          // 32 * 32 * 32 (B*H*W)
#define K_CODES 1024
#define C_DIM 256
#define HW 1024               // H*W = 32*32

// d_out layout (float elements), tuple concatenated flat in return order:
// distances [N,K] | indices [N] (as float) | encodings [N,K] | perplexity [1]
#define OFF_DIST 0
#define OFF_IDX  (N_ROWS * K_CODES)
#define OFF_ENC  (OFF_IDX + N_ROWS)
#define OFF_PERP (OFF_ENC + N_ROWS * K_CODES)

typedef __attribute__((ext_vector_type(8))) short short8;   // 8 bf16 (4 VGPR)
typedef __attribute__((ext_vector_type(4))) float f32x4;    // MFMA acc

// ---- bf16 split helpers (bit-level, round-to-nearest-even) ------------------
__device__ inline unsigned short bf16_rn(float x) {
    unsigned int u = __float_as_uint(x);
    unsigned int r = u + 0x7FFFu + ((u >> 16) & 1u);
    return (unsigned short)(r >> 16);
}
__device__ inline float bf16_to_f(unsigned short h) {
    return __uint_as_float(((unsigned int)h) << 16);
}

// ---- async global->LDS, 16B per lane (dest = wave-uniform base + lane*16) ---
__device__ __forceinline__ void gl2lds16(const unsigned short* g, char* l) {
    __builtin_amdgcn_global_load_lds(
        (const __attribute__((address_space(1))) unsigned int*)g,
        (__attribute__((address_space(3))) unsigned int*)l, 16, 0, 0);
}

// ------- fused prep: z NCHW->NHWC hi/lo + zsq  |  codebook hi/lo + esq -------
// blocks 0..255: z role (b = bid>>3, hw-tile = bid&7). blocks 256..511: cb.
__global__ __launch_bounds__(256) void prep_kernel(
        const float* __restrict__ z, const float* __restrict__ cb,
        unsigned short* __restrict__ z_hi, unsigned short* __restrict__ z_lo,
        unsigned short* __restrict__ cb_hi, unsigned short* __restrict__ cb_lo,
        float* __restrict__ zsq, float* __restrict__ esq) {
    const int bid = blockIdx.x;
    const int t = threadIdx.x;

    if (bid >= 256) {          // ---- codebook role: wave per row ----
        const int lane = t & 63;
        const int k = (bid - 256) * 4 + (t >> 6);
        float4 v = *reinterpret_cast<const float4*>(cb + (size_t)k * C_DIM + lane * 4);
        float s = v.x * v.x + v.y * v.y + v.z * v.z + v.w * v.w;
        ushort4 h, l;
        h.x = bf16_rn(v.x); l.x = bf16_rn(v.x - bf16_to_f(h.x));
        h.y = bf16_rn(v.y); l.y = bf16_rn(v.y - bf16_to_f(h.y));
        h.z = bf16_rn(v.z); l.z = bf16_rn(v.z - bf16_to_f(h.z));
        h.w = bf16_rn(v.w); l.w = bf16_rn(v.w - bf16_to_f(h.w));
        *reinterpret_cast<ushort4*>(cb_hi + (size_t)k * C_DIM + lane * 4) = h;
        *reinterpret_cast<ushort4*>(cb_lo + (size_t)k * C_DIM + lane * 4) = l;
#pragma unroll
        for (int m = 1; m < 64; m <<= 1) s += __shfl_xor(s, m);
        if (lane == 0) esq[k] = s;
        return;
    }

    // ---- z role: LDS-tiled NCHW -> NHWC transpose + hi/lo split + zsq ----
    __shared__ float st[64][132];          // [c][hw]
    const int b = bid >> 3;
    const int hw0 = (bid & 7) * 128;

    const int c_r  = t >> 5;               // 0..7  (read role)
    const int hw_r = (t & 31) * 4;
    const int hw_w = t >> 1;               // 0..127 (write role)
    const int ch   = (t & 1) * 32;
    const int n    = b * HW + hw0 + hw_w;

    float zacc = 0.f;

    for (int c0 = 0; c0 < C_DIM; c0 += 64) {
#pragma unroll
        for (int it = 0; it < 8; ++it) {
            int c_l = it * 8 + c_r;
            float4 v = *reinterpret_cast<const float4*>(
                z + (size_t)b * (C_DIM * HW) + (size_t)(c0 + c_l) * HW + hw0 + hw_r);
            *reinterpret_cast<float4*>(&st[c_l][hw_r]) = v;
        }
        __syncthreads();

        short8 hv[4], lv[4];
#pragma unroll
        for (int j = 0; j < 32; ++j) {
            float x = st[ch + j][hw_w];
            unsigned short h = bf16_rn(x);
            unsigned short lo = bf16_rn(x - bf16_to_f(h));
            hv[j >> 3][j & 7] = (short)h;
            lv[j >> 3][j & 7] = (short)lo;
            zacc = fmaf(x, x, zacc);
        }
        unsigned short* hp = z_hi + (size_t)n * C_DIM + c0 + ch;
        unsigned short* lp = z_lo + (size_t)n * C_DIM + c0 + ch;
#pragma unroll
        for (int q = 0; q < 4; ++q) {
            *reinterpret_cast<short8*>(hp + q * 8) = hv[q];
            *reinterpret_cast<short8*>(lp + q * 8) = lv[q];
        }
        __syncthreads();
    }
    float o = __shfl_xor(zacc, 1);
    if ((t & 1) == 0) zsq[n] = zacc + o;
}

// -------- distances: m97-structure bf16 GEMM over virtual K=768 --------------
// 128x256 tile, BK=32, 8 waves (2x4, 64x64 each), double-buffered LDS fed by
// global_load_lds(16B), ds_read_b128 fragments, 16 MFMA / wave / K-step.
// Virtual K: steps 0-7 = Ah*Bh, 8-15 = Ah*Bl, 16-23 = Al*Bh (c0 = (s&7)*32).
// Grid 1024 = 256 row-tiles x 4 col-tiles, XCD-swizzled (col-tile fastest).
#define KSTEPS 24

__global__ __launch_bounds__(512) void dist_mfma_kernel(
        const unsigned short* __restrict__ z_hi,
        const unsigned short* __restrict__ z_lo,
        const unsigned short* __restrict__ cb_hi,
        const unsigned short* __restrict__ cb_lo,
        const float* __restrict__ zsq, const float* __restrict__ esq,
        float* __restrict__ dist, float2* __restrict__ partial) {
    __shared__ __align__(16) unsigned short As[2][128 * 32];   // 16 KB
    __shared__ __align__(16) unsigned short Bs[2][256 * 32];   // 32 KB
    __shared__ float2 pb[128][4];                              //  4 KB

    const int t = threadIdx.x;
    const int lane = t & 63, wid = t >> 6;
    const int wy = wid >> 2, wx = wid & 3;      // 2 x 4 wave grid
    const int l15 = lane & 15, l4 = lane >> 4;

    // XCD-aware swizzle: 1024 blocks, 8 XCDs, 128 contiguous per XCD.
    const int swz = (blockIdx.x & 7) * 128 + (blockIdx.x >> 3);
    const int kbi = swz & 3;                    // col tile fastest -> shares A
    const int kb = kbi * 256;
    const int nb = (swz >> 2) * 128;

    // staging: A 512 chunks (t), B 1024 chunks (t, 512+t); 16B each.
#define STAGE(buf_, s_) do {                                                   \
        const int sp_ = (s_) >> 3;                                             \
        const int sc0_ = ((s_) & 7) * 32;                                      \
        const unsigned short* Ap_ = (sp_ == 2) ? z_lo : z_hi;                  \
        const unsigned short* Bp_ = (sp_ == 1) ? cb_lo : cb_hi;                \
        const int wb_ = (t & ~63) * 16;                                        \
        gl2lds16(Ap_ + (size_t)(nb + (t >> 2)) * C_DIM + sc0_ + (t & 3) * 8,   \
                 (char*)(&As[buf_][0]) + wb_);                                 \
        gl2lds16(Bp_ + (size_t)(kb + (t >> 2)) * C_DIM + sc0_ + (t & 3) * 8,   \
                 (char*)(&Bs[buf_][0]) + wb_);                                 \
        gl2lds16(Bp_ + (size_t)(kb + 128 + (t >> 2)) * C_DIM + sc0_ + (t & 3) * 8, \
                 (char*)(&Bs[buf_][0]) + 8192 + wb_);                          \
    } while (0)

    f32x4 acc[4][4] = {};

    STAGE(0, 0);
    __syncthreads();

    for (int s = 0; s < KSTEPS; ++s) {
        const int cur = s & 1;
        if (s < KSTEPS - 1) STAGE(cur ^ 1, s + 1);

        short8 av[4], bv[4];
#pragma unroll
        for (int mi = 0; mi < 4; ++mi)
            av[mi] = *reinterpret_cast<const short8*>(
                &As[cur][(wy * 64 + mi * 16 + l15) * 32 + l4 * 8]);
#pragma unroll
        for (int ci = 0; ci < 4; ++ci)
            bv[ci] = *reinterpret_cast<const short8*>(
                &Bs[cur][(wx * 64 + ci * 16 + l15) * 32 + l4 * 8]);

#pragma unroll
        for (int mi = 0; mi < 4; ++mi)
#pragma unroll
            for (int ci = 0; ci < 4; ++ci)
                acc[mi][ci] = __builtin_amdgcn_mfma_f32_16x16x32_bf16(
                    av[mi], bv[ci], acc[mi][ci], 0, 0, 0);
        __syncthreads();
    }
#undef STAGE

    // ---- epilogue: dist = zsq + esq - 2*dot; write + per-row partial argmin
    float zsv[4][4];
#pragma unroll
    for (int mi = 0; mi < 4; ++mi)
#pragma unroll
        for (int r = 0; r < 4; ++r)
            zsv[mi][r] = zsq[nb + wy * 64 + mi * 16 + l4 * 4 + r];
    float esv[4];
#pragma unroll
    for (int ci = 0; ci < 4; ++ci)
        esv[ci] = esq[kb + wx * 64 + ci * 16 + l15];

    float best[4][4];
    int bidx[4][4];
#pragma unroll
    for (int mi = 0; mi < 4; ++mi)
#pragma unroll
        for (int r = 0; r < 4; ++r) { best[mi][r] = 1e30f; bidx[mi][r] = K_CODES; }

#pragma unroll
    for (int mi = 0; mi < 4; ++mi) {
#pragma unroll
        for (int r = 0; r < 4; ++r) {
            int row = nb + wy * 64 + mi * 16 + l4 * 4 + r;
            float* drow = dist + (size_t)row * K_CODES;
#pragma unroll
            for (int ci = 0; ci < 4; ++ci) {     // ci ascending = k ascending
                int col = kb + wx * 64 + ci * 16 + l15;
                float d = zsv[mi][r] + esv[ci] - 2.f * acc[mi][ci][r];
                drow[col] = d;
                if (d < best[mi][r]) { best[mi][r] = d; bidx[mi][r] = col; }
            }
        }
    }

    // reduce across the 16-lane column group (xor masks 1,2,4,8 vary l15 only)
#pragma unroll
    for (int m = 1; m < 16; m <<= 1) {
#pragma unroll
        for (int mi = 0; mi < 4; ++mi)
#pragma unroll
            for (int r = 0; r < 4; ++r) {
                float ob = __shfl_xor(best[mi][r], m);
                int   oi = __shfl_xor(bidx[mi][r], m);
                if (ob < best[mi][r] || (ob == best[mi][r] && oi < bidx[mi][r])) {
                    best[mi][r] = ob; bidx[mi][r] = oi;
                }
            }
    }

    if (l15 == 0) {
#pragma unroll
        for (int mi = 0; mi < 4; ++mi)
#pragma unroll
            for (int r = 0; r < 4; ++r) {
                int rl = wy * 64 + mi * 16 + l4 * 4 + r;
                pb[rl][wx] = make_float2(best[mi][r], (float)bidx[mi][r]);
            }
    }
    __syncthreads();
    if (t < 128) {
        float2 bv2 = pb[t][0];
#pragma unroll
        for (int w = 1; w < 4; ++w) {
            float2 c = pb[t][w];              // ascending wx = ascending k
            if (c.x < bv2.x) bv2 = c;
        }
        partial[(size_t)kbi * N_ROWS + nb + t] = bv2;
    }
}

// -------- combine 4 kb-partials + one-hot encodings (fused) ------------------
__global__ __launch_bounds__(256) void combenc_kernel(
        const float2* __restrict__ partial, float* __restrict__ idx_out,
        int* __restrict__ idx_int, float* __restrict__ enc) {
    __shared__ int sidx[16];
    const int t = threadIdx.x;
    const int r0 = blockIdx.x * 16;
    if (t < 16) {
        int n = r0 + t;
        float2 bv = partial[n];
#pragma unroll
        for (int kb = 1; kb < 4; ++kb) {      // ascending kb = ascending k
            float2 c = partial[(size_t)kb * N_ROWS + n];
            if (c.x < bv.x) bv = c;
        }
        idx_out[n] = bv.y;
        idx_int[n] = (int)bv.y;
        sidx[t] = (int)bv.y;
    }
    __syncthreads();
    const int k0 = t * 4;
#pragma unroll 4
    for (int r = 0; r < 16; ++r) {
        int bi = sidx[r];
        float4 v;
        v.x = (k0 + 0 == bi) ? 1.0f : 0.0f;
        v.y = (k0 + 1 == bi) ? 1.0f : 0.0f;
        v.z = (k0 + 2 == bi) ? 1.0f : 0.0f;
        v.w = (k0 + 3 == bi) ? 1.0f : 0.0f;
        *reinterpret_cast<float4*>(enc + (size_t)(r0 + r) * K_CODES + k0) = v;
    }
}

// ---------------- perplexity: LDS histogram of idxi + reduce -----------------
__global__ __launch_bounds__(1024) void perp_kernel(const int* __restrict__ idxi,
                                                    float* __restrict__ out) {
    __shared__ int hist[K_CODES];
    __shared__ float wsum[16];
    const int t = threadIdx.x;
    hist[t] = 0;
    __syncthreads();
    for (int n = t; n < N_ROWS; n += 1024)
        atomicAdd(&hist[idxi[n]], 1);
    __syncthreads();
    float p = (float)hist[t] * (1.0f / (float)N_ROWS);
    float s = p * logf(p + 1e-10f);
#pragma unroll
    for (int off = 32; off > 0; off >>= 1) s += __shfl_down(s, off);
    if ((t & 63) == 0) wsum[t >> 6] = s;
    __syncthreads();
    if (t == 0) {
        float tot = 0.f;
#pragma unroll
        for (int w = 0; w < 16; ++w) tot += wsum[w];
        out[0] = expf(-tot);
    }
}

extern "C" void kernel_launch(void* const* d_in, const int* in_sizes, int n_in,
                              void* d_out, int out_size, void* d_ws, size_t ws_size,
                              hipStream_t stream) {
    const float* z  = (const float*)d_in[0];   // [32,256,32,32]
    const float* cb = (const float*)d_in[1];   // [1024,256]
    float* out  = (float*)d_out;
    float* dist = out + OFF_DIST;
    float* idxo = out + OFF_IDX;
    float* enc  = out + OFF_ENC;
    float* perp = out + OFF_PERP;

    // ws layout (bytes), ~1.3 MB
    char* wsb = (char*)d_ws;
    float*  zsq  = (float*)(wsb + 0);          // 131072 B
    float*  esq  = (float*)(wsb + 131072);     //   4096 B
    int*    idxi = (int*)(wsb + 135168);       // 131072 B
    float2* part = (float2*)(wsb + 266240);    // 4*32768*8 = 1048576 B

    // Big staging buffers live in the enc region of d_out (128 MB): written by
    // prep, read by dist, then overwritten by combenc (strict stream order).
    unsigned short* z_hi  = (unsigned short*)enc;
    unsigned short* z_lo  = z_hi + (size_t)N_ROWS * C_DIM;     // +16 MB
    unsigned short* cb_hi = z_lo + (size_t)N_ROWS * C_DIM;     // +32 MB
    unsigned short* cb_lo = cb_hi + (size_t)K_CODES * C_DIM;   // +32.5 MB

    prep_kernel<<<512, 256, 0, stream>>>(z, cb, z_hi, z_lo, cb_hi, cb_lo, zsq, esq);
    dist_mfma_kernel<<<1024, 512, 0, stream>>>(z_hi, z_lo, cb_hi, cb_lo,
                                               zsq, esq, dist, part);
    combenc_kernel<<<N_ROWS / 16, 256, 0, stream>>>(part, idxo, idxi, enc);
    perp_kernel<<<1, 1024, 0, stream>>>(idxi, perp);
}